// Round 1
// baseline (300.521 us; speedup 1.0000x reference)
//
#include <hip/hip_runtime.h>
#include <math.h>

#define N_TOK 32768
#define DIM   512
#define NEXP  16
#define CAP   2457
#define CAPP  2464
#define NCHUNK 512   // chunks of 64 tokens

typedef __attribute__((ext_vector_type(8))) short   short8;
typedef __attribute__((ext_vector_type(4))) float   floatx4;

__device__ __forceinline__ short f2bf(float f) {
  unsigned u = __builtin_bit_cast(unsigned, f);
  unsigned r = u + 0x7FFFu + ((u >> 16) & 1u);   // round-to-nearest-even bf16
  return (short)(r >> 16);
}

// ---------------- K1: router (softmax top-1) + per-chunk histogram ----------
// 512 blocks x 256 threads; each wave handles 16 tokens (wave-per-token dots).
__global__ __launch_bounds__(256) void router_k(
    const float* __restrict__ x, const float* __restrict__ sw,
    const float* __restrict__ sb, int* __restrict__ route,
    float* __restrict__ prob, int* __restrict__ hist) {
  __shared__ int lcnt[NEXP];
  int tid = threadIdx.x;
  if (tid < NEXP) lcnt[tid] = 0;
  __syncthreads();
  int wv = tid >> 6, lane = tid & 63;
  int base = blockIdx.x * 64 + wv * 16;
  for (int i = 0; i < 16; ++i) {
    int t = base + i;
    const float4* xr = (const float4*)(x + (size_t)t * DIM);
    float4 xa = xr[lane], xb = xr[lane + 64];
    float lg[NEXP];
#pragma unroll
    for (int e = 0; e < NEXP; ++e) {
      const float4* wr = (const float4*)(sw + e * DIM);
      float4 wa = wr[lane], wb = wr[lane + 64];
      float p = xa.x*wa.x + xa.y*wa.y + xa.z*wa.z + xa.w*wa.w
              + xb.x*wb.x + xb.y*wb.y + xb.z*wb.z + xb.w*wb.w;
#pragma unroll
      for (int m = 1; m < 64; m <<= 1) p += __shfl_xor(p, m, 64);
      lg[e] = p + sb[e];
    }
    if (lane == 0) {
      int arg = 0; float mx = lg[0];
#pragma unroll
      for (int e = 1; e < NEXP; ++e) if (lg[e] > mx) { mx = lg[e]; arg = e; }
      float s = 0.f;
#pragma unroll
      for (int e = 0; e < NEXP; ++e) s += expf(lg[e] - mx);
      route[t] = arg;
      prob[t]  = 1.0f / s;            // max softmax prob
      atomicAdd(&lcnt[arg], 1);
    }
  }
  __syncthreads();
  if (tid < NEXP) hist[blockIdx.x * NEXP + tid] = lcnt[tid];
}

// ---------------- K2: exclusive scan of chunk histograms --------------------
// 1 block x 256 threads: thread (g,e) handles 32 chunks for expert e.
__global__ __launch_bounds__(256) void scan_k(
    const int* __restrict__ hist, int* __restrict__ offs,
    int* __restrict__ counts) {
  __shared__ int part[16][NEXP];
  __shared__ int base[16][NEXP];
  int e = threadIdx.x & 15, g = threadIdx.x >> 4;   // g in [0,16)
  int s = 0;
  for (int b = g * 32; b < g * 32 + 32; ++b) s += hist[b * NEXP + e];
  part[g][e] = s;
  __syncthreads();
  if (g == 0) {
    int run = 0;
#pragma unroll
    for (int gg = 0; gg < 16; ++gg) { base[gg][e] = run; run += part[gg][e]; }
    counts[e] = run;
  }
  __syncthreads();
  int run = base[g][e];
  for (int b = g * 32; b < g * 32 + 32; ++b) {
    offs[b * NEXP + e] = run;
    run += hist[b * NEXP + e];
  }
}

// ---------------- K3: per-token position, dispatch lists, dropped tokens ----
__global__ __launch_bounds__(64) void pos_k(
    const int* __restrict__ route, const float* __restrict__ prob,
    const int* __restrict__ offs, const float* __restrict__ x,
    float* __restrict__ out, int* __restrict__ lists) {
  __shared__ int sr[64];
  int tid = threadIdx.x;
  int t = blockIdx.x * 64 + tid;
  int r = route[t];
  sr[tid] = r;
  __syncthreads();
  int rank = 0;
  for (int j = 0; j < tid; ++j) rank += (sr[j] == r);
  int pos = offs[blockIdx.x * NEXP + r] + rank;
  if (pos < CAP) {
    lists[r * CAPP + pos] = t;
  } else {
    // dropped token: passthrough x * prob
    float p = prob[t];
    const float4* xr = (const float4*)(x + (size_t)t * DIM);
    float4* o = (float4*)(out + (size_t)t * DIM);
    for (int d = 0; d < DIM / 4; ++d) {
      float4 v = xr[d];
      v.x *= p; v.y *= p; v.z *= p; v.w *= p;
      o[d] = v;
    }
  }
}

// ---------------- K4: grouped GEMM, bf16 MFMA, gathered rows ----------------
// grid (4 col-tiles, 20 row-tiles, 16 experts), 256 threads = 4 waves.
// Tile 128x128, BK=64. y[t] = x[t] @ W_e^T + b_e, out[t] = y*prob[t].
#define BM 128
#define BN 128
#define BK 64
#define LDT 72   // BK + 8 pad (shorts)

__global__ __launch_bounds__(256) void gemm_k(
    const float* __restrict__ x, const float* __restrict__ ew,
    const float* __restrict__ eb, const int* __restrict__ lists,
    const int* __restrict__ counts, const float* __restrict__ prob,
    float* __restrict__ out) {
  int e = blockIdx.z;
  int cnt = counts[e]; if (cnt > CAP) cnt = CAP;
  int row0 = blockIdx.y * BM;
  if (row0 >= cnt) return;
  int col0 = blockIdx.x * BN;

  __shared__ short A_s[BM * LDT];
  __shared__ short B_s[BN * LDT];
  __shared__ int rowtok[BM];

  int tid = threadIdx.x;
  if (tid < BM) {
    int gr = row0 + tid;
    rowtok[tid] = (gr < cnt) ? lists[e * CAPP + gr] : 0;
  }
  __syncthreads();

  int wv = tid >> 6, lane = tid & 63;
  int q = lane >> 4, l16 = lane & 15;
  int wrow = (wv >> 1) * 64, wcol = (wv & 1) * 64;

  int arow = tid >> 1, ahalf = tid & 1;          // staging: 2 threads/row
  int at = rowtok[arow];
  const float* xrow  = x  + (size_t)at * DIM + ahalf * 32;
  const float* wrowp = ew + ((size_t)e * DIM + (size_t)(col0 + arow)) * DIM + ahalf * 32;

  floatx4 acc[4][4] = {};

  for (int k0 = 0; k0 < DIM; k0 += BK) {
    {
      const float4* src  = (const float4*)(xrow + k0);
      short8* dst  = (short8*)&A_s[arow * LDT + ahalf * 32];
      const float4* srcb = (const float4*)(wrowp + k0);
      short8* dstb = (short8*)&B_s[arow * LDT + ahalf * 32];
#pragma unroll
      for (int v = 0; v < 4; ++v) {
        float4 f0 = src[2 * v], f1 = src[2 * v + 1];
        short8 sv;
        sv[0] = f2bf(f0.x); sv[1] = f2bf(f0.y); sv[2] = f2bf(f0.z); sv[3] = f2bf(f0.w);
        sv[4] = f2bf(f1.x); sv[5] = f2bf(f1.y); sv[6] = f2bf(f1.z); sv[7] = f2bf(f1.w);
        dst[v] = sv;
        float4 g0 = srcb[2 * v], g1 = srcb[2 * v + 1];
        short8 tv;
        tv[0] = f2bf(g0.x); tv[1] = f2bf(g0.y); tv[2] = f2bf(g0.z); tv[3] = f2bf(g0.w);
        tv[4] = f2bf(g1.x); tv[5] = f2bf(g1.y); tv[6] = f2bf(g1.z); tv[7] = f2bf(g1.w);
        dstb[v] = tv;
      }
    }
    __syncthreads();
#pragma unroll
    for (int kk = 0; kk < BK; kk += 32) {
      short8 af[4], bf[4];
#pragma unroll
      for (int sm = 0; sm < 4; ++sm)
        af[sm] = *(const short8*)&A_s[(wrow + sm * 16 + l16) * LDT + kk + q * 8];
#pragma unroll
      for (int sn = 0; sn < 4; ++sn)
        bf[sn] = *(const short8*)&B_s[(wcol + sn * 16 + l16) * LDT + kk + q * 8];
#pragma unroll
      for (int sm = 0; sm < 4; ++sm)
#pragma unroll
        for (int sn = 0; sn < 4; ++sn)
          acc[sm][sn] = __builtin_amdgcn_mfma_f32_16x16x32_bf16(
              af[sm], bf[sn], acc[sm][sn], 0, 0, 0);
    }
    __syncthreads();
  }

  // epilogue: out[t][col] = (acc + bias) * prob[t]
#pragma unroll
  for (int sm = 0; sm < 4; ++sm) {
    int tt[4]; float pp[4]; int vld[4];
#pragma unroll
    for (int rg = 0; rg < 4; ++rg) {
      int rr = wrow + sm * 16 + q * 4 + rg;
      int gr = row0 + rr;
      vld[rg] = (gr < cnt);
      tt[rg]  = rowtok[rr];
      pp[rg]  = vld[rg] ? prob[tt[rg]] : 0.f;
    }
#pragma unroll
    for (int sn = 0; sn < 4; ++sn) {
      int col = col0 + wcol + sn * 16 + l16;
      float bias = eb[e * DIM + col];
#pragma unroll
      for (int rg = 0; rg < 4; ++rg)
        if (vld[rg])
          out[(size_t)tt[rg] * DIM + col] = (acc[sm][sn][rg] + bias) * pp[rg];
    }
  }
}

extern "C" void kernel_launch(void* const* d_in, const int* in_sizes, int n_in,
                              void* d_out, int out_size, void* d_ws, size_t ws_size,
                              hipStream_t stream) {
  const float* x  = (const float*)d_in[0];
  const float* sw = (const float*)d_in[1];
  const float* sb = (const float*)d_in[2];
  const float* ew = (const float*)d_in[3];
  const float* eb = (const float*)d_in[4];
  float* out = (float*)d_out;

  char* ws = (char*)d_ws;
  int*   route  = (int*)(ws + 0);         // 32768 * 4
  float* prob   = (float*)(ws + 131072);  // 32768 * 4
  int*   hist   = (int*)(ws + 262144);    // 512*16*4
  int*   offs   = (int*)(ws + 294912);    // 512*16*4
  int*   counts = (int*)(ws + 327680);    // 16*4 (+pad)
  int*   lists  = (int*)(ws + 327744);    // 16*2464*4

  hipLaunchKernelGGL(router_k, dim3(NCHUNK), dim3(256), 0, stream,
                     x, sw, sb, route, prob, hist);
  hipLaunchKernelGGL(scan_k, dim3(1), dim3(256), 0, stream, hist, offs, counts);
  hipLaunchKernelGGL(pos_k, dim3(NCHUNK), dim3(64), 0, stream,
                     route, prob, offs, x, out, lists);
  hipLaunchKernelGGL(gemm_k, dim3(4, 20, 16), dim3(256), 0, stream,
                     x, ew, eb, lists, counts, prob, out);
}

// Round 2
// 218.845 us; speedup vs baseline: 1.3732x; 1.3732x over previous
//
#include <hip/hip_runtime.h>
#include <math.h>

#define N_TOK 32768
#define DIM   512
#define NEXP  16
#define CAP   2457
#define CAPP  2464
#define NCHUNK 512   // chunks of 64 tokens

typedef __attribute__((ext_vector_type(8))) short   short8;
typedef __attribute__((ext_vector_type(4))) short   short4v;
typedef __attribute__((ext_vector_type(4))) float   floatx4;

__device__ __forceinline__ short f2bf(float f) {
  unsigned u = __builtin_bit_cast(unsigned, f);
  unsigned r = u + 0x7FFFu + ((u >> 16) & 1u);   // round-to-nearest-even bf16
  return (short)(r >> 16);
}

// ---------------- K1: router + fused x->bf16 conversion ---------------------
__global__ __launch_bounds__(256) void router_k(
    const float* __restrict__ x, const float* __restrict__ sw,
    const float* __restrict__ sb, int* __restrict__ route,
    float* __restrict__ prob, int* __restrict__ hist,
    short* __restrict__ x_bf) {
  __shared__ int lcnt[NEXP];
  int tid = threadIdx.x;
  if (tid < NEXP) lcnt[tid] = 0;
  __syncthreads();
  int wv = tid >> 6, lane = tid & 63;
  int base = blockIdx.x * 64 + wv * 16;

  float4 wA[NEXP], wB[NEXP];
#pragma unroll
  for (int e = 0; e < NEXP; ++e) {
    const float4* wr = (const float4*)(sw + e * DIM);
    wA[e] = wr[lane]; wB[e] = wr[lane + 64];
  }

  for (int i = 0; i < 16; ++i) {
    int t = base + i;
    const float4* xr = (const float4*)(x + (size_t)t * DIM);
    float4 xa = xr[lane], xb = xr[lane + 64];

    short4v sa, sbv;
    sa[0] = f2bf(xa.x); sa[1] = f2bf(xa.y); sa[2] = f2bf(xa.z); sa[3] = f2bf(xa.w);
    sbv[0] = f2bf(xb.x); sbv[1] = f2bf(xb.y); sbv[2] = f2bf(xb.z); sbv[3] = f2bf(xb.w);
    short4v* xo = (short4v*)(x_bf + (size_t)t * DIM);
    xo[lane] = sa; xo[lane + 64] = sbv;

    float p[NEXP];
#pragma unroll
    for (int e = 0; e < NEXP; ++e)
      p[e] = xa.x*wA[e].x + xa.y*wA[e].y + xa.z*wA[e].z + xa.w*wA[e].w
           + xb.x*wB[e].x + xb.y*wB[e].y + xb.z*wB[e].z + xb.w*wB[e].w;
#pragma unroll
    for (int m = 1; m < 64; m <<= 1) {
#pragma unroll
      for (int e = 0; e < NEXP; ++e) p[e] += __shfl_xor(p[e], m, 64);
    }
    if (lane == 0) {
      int arg = 0; float mx = p[0] + sb[0];
      float lg[NEXP];
      lg[0] = mx;
#pragma unroll
      for (int e = 1; e < NEXP; ++e) {
        lg[e] = p[e] + sb[e];
        if (lg[e] > mx) { mx = lg[e]; arg = e; }
      }
      float s = 0.f;
#pragma unroll
      for (int e = 0; e < NEXP; ++e) s += expf(lg[e] - mx);
      route[t] = arg;
      prob[t]  = 1.0f / s;
      atomicAdd(&lcnt[arg], 1);
    }
  }
  __syncthreads();
  if (tid < NEXP) hist[blockIdx.x * NEXP + tid] = lcnt[tid];
}

// ---------------- K1b: expert_w -> bf16 -------------------------------------
__global__ __launch_bounds__(256) void convw_k(
    const float* __restrict__ ew, short* __restrict__ w_bf) {
  int i = blockIdx.x * 256 + threadIdx.x;
  float4 f = ((const float4*)ew)[i];
  short4v s;
  s[0] = f2bf(f.x); s[1] = f2bf(f.y); s[2] = f2bf(f.z); s[3] = f2bf(f.w);
  ((short4v*)w_bf)[i] = s;
}

// ---------------- K2: exclusive scan of chunk histograms --------------------
__global__ __launch_bounds__(256) void scan_k(
    const int* __restrict__ hist, int* __restrict__ offs,
    int* __restrict__ counts) {
  __shared__ int part[16][NEXP];
  __shared__ int base[16][NEXP];
  int e = threadIdx.x & 15, g = threadIdx.x >> 4;
  int s = 0;
  for (int b = g * 32; b < g * 32 + 32; ++b) s += hist[b * NEXP + e];
  part[g][e] = s;
  __syncthreads();
  if (g == 0) {
    int run = 0;
#pragma unroll
    for (int gg = 0; gg < 16; ++gg) { base[gg][e] = run; run += part[gg][e]; }
    counts[e] = run;
  }
  __syncthreads();
  int run = base[g][e];
  for (int b = g * 32; b < g * 32 + 32; ++b) {
    offs[b * NEXP + e] = run;
    run += hist[b * NEXP + e];
  }
}

// ---------------- K3: positions via ballot ----------------------------------
__global__ __launch_bounds__(64) void pos_k(
    const int* __restrict__ route, const float* __restrict__ prob,
    const int* __restrict__ offs, const float* __restrict__ x,
    float* __restrict__ out, int* __restrict__ lists) {
  int tid = threadIdx.x;
  int t = blockIdx.x * 64 + tid;
  int r = route[t];
  unsigned long long lower = (1ull << tid) - 1ull;
  int rank = 0;
#pragma unroll
  for (int e = 0; e < NEXP; ++e) {
    unsigned long long m = __ballot(r == e);
    if (r == e) rank = __popcll(m & lower);
  }
  int pos = offs[blockIdx.x * NEXP + r] + rank;
  if (pos < CAP) {
    lists[r * CAPP + pos] = t;
  } else {
    float p = prob[t];
    const float4* xr = (const float4*)(x + (size_t)t * DIM);
    float4* o = (float4*)(out + (size_t)t * DIM);
    for (int d = 0; d < DIM / 4; ++d) {
      float4 v = xr[d];
      v.x *= p; v.y *= p; v.z *= p; v.w *= p;
      o[d] = v;
    }
  }
}

// ---------------- K4: grouped GEMM, m97 structure ---------------------------
#define BM 128
#define BN 128
#define BKS 64

__global__ __launch_bounds__(256, 2) void gemm_k(
    const short* __restrict__ x_bf, const short* __restrict__ w_bf,
    const float* __restrict__ eb, const int* __restrict__ lists,
    const int* __restrict__ counts, const float* __restrict__ prob,
    float* __restrict__ out) {
  int e = blockIdx.z;
  int cnt = counts[e]; if (cnt > CAP) cnt = CAP;
  int row0 = blockIdx.y * BM;
  if (row0 >= cnt) return;
  int col0 = blockIdx.x * BN;

  __shared__ short A_s[BM * BKS];
  __shared__ short B_s[BN * BKS];
  __shared__ int rowtok[BM];

  int tid = threadIdx.x;
  if (tid < BM) {
    int gr = row0 + tid;
    rowtok[tid] = (gr < cnt) ? lists[e * CAPP + gr] : 0;
  }
  __syncthreads();

  int wv = tid >> 6, lane = tid & 63;
  int q = lane >> 4, l16 = lane & 15;
  int wrow = (wv >> 1) * 64, wcol = (wv & 1) * 64;

  // staging: per wave 32 rows x 8 chunks of 16B; lane -> (row=lane>>3, phys c=lane&7)
  // source logical chunk g = c ^ (row&7)  =>  LDS phys p holds logical p^(row&7)
  int r_loc = lane >> 3, c = lane & 7;
  int g = c ^ r_loc;
  const short* ga[4]; const short* gb[4];
  short* la[4]; short* lb[4];
#pragma unroll
  for (int t4 = 0; t4 < 4; ++t4) {
    int row = wv * 32 + t4 * 8 + r_loc;
    ga[t4] = x_bf + (size_t)rowtok[row] * DIM + g * 8;
    gb[t4] = w_bf + (size_t)(e * DIM + col0 + row) * DIM + g * 8;
    la[t4] = &A_s[(wv * 32 + t4 * 8) * BKS];   // wave-uniform base
    lb[t4] = &B_s[(wv * 32 + t4 * 8) * BKS];
  }

  floatx4 acc[4][4] = {};

  for (int k0 = 0; k0 < DIM; k0 += BKS) {
#pragma unroll
    for (int t4 = 0; t4 < 4; ++t4) {
      __builtin_amdgcn_global_load_lds(
          (const __attribute__((address_space(1))) void*)(ga[t4] + k0),
          (__attribute__((address_space(3))) void*)(la[t4]), 16, 0, 0);
      __builtin_amdgcn_global_load_lds(
          (const __attribute__((address_space(1))) void*)(gb[t4] + k0),
          (__attribute__((address_space(3))) void*)(lb[t4]), 16, 0, 0);
    }
    __syncthreads();
#pragma unroll
    for (int kk = 0; kk < 2; ++kk) {
      short8 af[4], bfv[4];
      int ckbase = kk * 4 + q;
#pragma unroll
      for (int sm = 0; sm < 4; ++sm) {
        int row = wrow + sm * 16 + l16;
        int ph = ckbase ^ (row & 7);
        af[sm] = *(const short8*)&A_s[row * BKS + ph * 8];
      }
#pragma unroll
      for (int sn = 0; sn < 4; ++sn) {
        int row = wcol + sn * 16 + l16;
        int ph = ckbase ^ (row & 7);
        bfv[sn] = *(const short8*)&B_s[row * BKS + ph * 8];
      }
#pragma unroll
      for (int sm = 0; sm < 4; ++sm)
#pragma unroll
        for (int sn = 0; sn < 4; ++sn)
          acc[sm][sn] = __builtin_amdgcn_mfma_f32_16x16x32_bf16(
              af[sm], bfv[sn], acc[sm][sn], 0, 0, 0);
    }
    __syncthreads();
  }

#pragma unroll
  for (int sm = 0; sm < 4; ++sm) {
    int tt[4]; float pp[4]; int vld[4];
#pragma unroll
    for (int rg = 0; rg < 4; ++rg) {
      int rr = wrow + sm * 16 + q * 4 + rg;
      int gr = row0 + rr;
      vld[rg] = (gr < cnt);
      tt[rg]  = rowtok[rr];
      pp[rg]  = vld[rg] ? prob[tt[rg]] : 0.f;
    }
#pragma unroll
    for (int sn = 0; sn < 4; ++sn) {
      int col = col0 + wcol + sn * 16 + l16;
      float bias = eb[e * DIM + col];
#pragma unroll
      for (int rg = 0; rg < 4; ++rg)
        if (vld[rg])
          out[(size_t)tt[rg] * DIM + col] = (acc[sm][sn][rg] + bias) * pp[rg];
    }
  }
}

extern "C" void kernel_launch(void* const* d_in, const int* in_sizes, int n_in,
                              void* d_out, int out_size, void* d_ws, size_t ws_size,
                              hipStream_t stream) {
  const float* x  = (const float*)d_in[0];
  const float* sw = (const float*)d_in[1];
  const float* sb = (const float*)d_in[2];
  const float* ew = (const float*)d_in[3];
  const float* eb = (const float*)d_in[4];
  float* out = (float*)d_out;

  char* ws = (char*)d_ws;
  int*   route  = (int*)(ws + 0);
  float* prob   = (float*)(ws + 131072);
  int*   hist   = (int*)(ws + 262144);
  int*   offs   = (int*)(ws + 294912);
  int*   counts = (int*)(ws + 327680);
  int*   lists  = (int*)(ws + 327744);
  short* x_bf   = (short*)(ws + (1 << 20));
  short* w_bf   = (short*)(ws + (1 << 20) + 33554432);

  hipLaunchKernelGGL(router_k, dim3(NCHUNK), dim3(256), 0, stream,
                     x, sw, sb, route, prob, hist, x_bf);
  hipLaunchKernelGGL(convw_k, dim3(NEXP * DIM * DIM / 4 / 256), dim3(256), 0, stream,
                     ew, w_bf);
  hipLaunchKernelGGL(scan_k, dim3(1), dim3(256), 0, stream, hist, offs, counts);
  hipLaunchKernelGGL(pos_k, dim3(NCHUNK), dim3(64), 0, stream,
                     route, prob, offs, x, out, lists);
  hipLaunchKernelGGL(gemm_k, dim3(4, 20, 16), dim3(256), 0, stream,
                     x_bf, w_bf, eb, lists, counts, prob, out);
}

// Round 3
// 184.697 us; speedup vs baseline: 1.6271x; 1.1849x over previous
//
#include <hip/hip_runtime.h>
#include <math.h>

#define N_TOK 32768
#define DIM   512
#define NEXP  16
#define CAP   2457
#define CAPP  2464
#define NCHUNK 512   // chunks of 64 tokens

typedef __attribute__((ext_vector_type(8))) short   short8;
typedef __attribute__((ext_vector_type(4))) short   short4v;
typedef __attribute__((ext_vector_type(4))) float   floatx4;

__device__ __forceinline__ short f2bf(float f) {
  unsigned u = __builtin_bit_cast(unsigned, f);
  unsigned r = u + 0x7FFFu + ((u >> 16) & 1u);   // round-to-nearest-even bf16
  return (short)(r >> 16);
}
__device__ __forceinline__ float bf2f(short h) {
  return __builtin_bit_cast(float, ((unsigned)(unsigned short)h) << 16);
}

// ---------------- K1: MFMA router (split-bf16 hi/lo, 4-term) ----------------
// 512 blocks x 256 threads; wave = 16 tokens via 16x16x32 MFMA (M=token,
// N=expert). Fuses x->bf16 conversion and expert_w->bf16 conversion.
#define LGP 17
__global__ __launch_bounds__(256) void router_k(
    const float* __restrict__ x, const float* __restrict__ sw,
    const float* __restrict__ sb, const float* __restrict__ ew,
    int* __restrict__ route, float* __restrict__ prob, int* __restrict__ hist,
    short* __restrict__ x_bf, short* __restrict__ w_bf) {
  __shared__ short swh[16][520];   // sw hi, row pad 520 shorts (2-way banks, free)
  __shared__ short swl[16][520];   // sw lo
  __shared__ float lgt[64][LGP];   // logits [token][expert]
  __shared__ float sbs[NEXP];

  int tid = threadIdx.x;

  // --- folded convw: this block converts 2048 float4 of expert_w ---
  {
    const float4* src = (const float4*)ew;
    short4v* dst = (short4v*)w_bf;
    int base = blockIdx.x * 2048 + tid;
#pragma unroll
    for (int i = 0; i < 8; ++i) {
      float4 f = src[base + i * 256];
      short4v s;
      s[0] = f2bf(f.x); s[1] = f2bf(f.y); s[2] = f2bf(f.z); s[3] = f2bf(f.w);
      dst[base + i * 256] = s;
    }
  }

  // --- stage sw hi/lo into LDS (2048 float4 total, 8 per thread) ---
  {
    int idx = tid;
#pragma unroll
    for (int i = 0; i < 8; ++i, idx += 256) {
      int e = idx >> 7, k4 = idx & 127;
      float4 f = ((const float4*)(sw + e * DIM))[k4];
      short4v h, l;
      h[0] = f2bf(f.x); h[1] = f2bf(f.y); h[2] = f2bf(f.z); h[3] = f2bf(f.w);
      l[0] = f2bf(f.x - bf2f(h[0]));
      l[1] = f2bf(f.y - bf2f(h[1]));
      l[2] = f2bf(f.z - bf2f(h[2]));
      l[3] = f2bf(f.w - bf2f(h[3]));
      *(short4v*)&swh[e][k4 * 4] = h;
      *(short4v*)&swl[e][k4 * 4] = l;
    }
  }
  if (tid < NEXP) sbs[tid] = sb[tid];
  __syncthreads();

  int wv = tid >> 6, lane = tid & 63, q = lane >> 4, l16 = lane & 15;
  // A-frag: lane holds A[m=l16][k=q*8+j]; B-frag: B[n=l16][k=q*8+j]
  int row = blockIdx.x * 64 + wv * 16 + l16;          // token id
  const float* xr = x + (size_t)row * DIM;
  short* xbr = x_bf + (size_t)row * DIM;

  floatx4 acc = {};
#pragma unroll 4
  for (int kc = 0; kc < 16; ++kc) {
    int k0 = kc * 32 + q * 8;
    float4 f0 = *(const float4*)(xr + k0);
    float4 f1 = *(const float4*)(xr + k0 + 4);
    short8 hi, lo;
    hi[0] = f2bf(f0.x); hi[1] = f2bf(f0.y); hi[2] = f2bf(f0.z); hi[3] = f2bf(f0.w);
    hi[4] = f2bf(f1.x); hi[5] = f2bf(f1.y); hi[6] = f2bf(f1.z); hi[7] = f2bf(f1.w);
    lo[0] = f2bf(f0.x - bf2f(hi[0])); lo[1] = f2bf(f0.y - bf2f(hi[1]));
    lo[2] = f2bf(f0.z - bf2f(hi[2])); lo[3] = f2bf(f0.w - bf2f(hi[3]));
    lo[4] = f2bf(f1.x - bf2f(hi[4])); lo[5] = f2bf(f1.y - bf2f(hi[5]));
    lo[6] = f2bf(f1.z - bf2f(hi[6])); lo[7] = f2bf(f1.w - bf2f(hi[7]));
    *(short8*)(xbr + k0) = hi;                        // fused x_bf write
    short8 bh = *(const short8*)&swh[l16][k0];
    short8 bl = *(const short8*)&swl[l16][k0];
    acc = __builtin_amdgcn_mfma_f32_16x16x32_bf16(hi, bh, acc, 0, 0, 0);
    acc = __builtin_amdgcn_mfma_f32_16x16x32_bf16(lo, bh, acc, 0, 0, 0);
    acc = __builtin_amdgcn_mfma_f32_16x16x32_bf16(hi, bl, acc, 0, 0, 0);
    acc = __builtin_amdgcn_mfma_f32_16x16x32_bf16(lo, bl, acc, 0, 0, 0);
  }
  // C layout: col=l16=expert, row=q*4+reg=token (within wave's 16)
#pragma unroll
  for (int r = 0; r < 4; ++r)
    lgt[wv * 16 + q * 4 + r][l16] = acc[r];
  __syncthreads();

  // --- all-lane softmax: wave 0, thread t = token t of this block ---
  if (tid < 64) {
    int t = blockIdx.x * 64 + tid;
    float lg[NEXP];
#pragma unroll
    for (int e = 0; e < NEXP; ++e) lg[e] = lgt[tid][e] + sbs[e];
    int arg = 0; float mx = lg[0];
#pragma unroll
    for (int e = 1; e < NEXP; ++e)
      if (lg[e] > mx) { mx = lg[e]; arg = e; }
    float s = 0.f;
#pragma unroll
    for (int e = 0; e < NEXP; ++e) s += expf(lg[e] - mx);
    route[t] = arg;
    prob[t]  = 1.0f / s;
#pragma unroll
    for (int e = 0; e < NEXP; ++e) {
      unsigned long long m = __ballot(arg == e);
      if (tid == e) hist[blockIdx.x * NEXP + e] = __popcll(m);
    }
  }
}

// ---------------- K2: exclusive scan of chunk histograms --------------------
__global__ __launch_bounds__(256) void scan_k(
    const int* __restrict__ hist, int* __restrict__ offs,
    int* __restrict__ counts) {
  __shared__ int part[16][NEXP];
  __shared__ int base[16][NEXP];
  int e = threadIdx.x & 15, g = threadIdx.x >> 4;
  int s = 0;
  for (int b = g * 32; b < g * 32 + 32; ++b) s += hist[b * NEXP + e];
  part[g][e] = s;
  __syncthreads();
  if (g == 0) {
    int run = 0;
#pragma unroll
    for (int gg = 0; gg < 16; ++gg) { base[gg][e] = run; run += part[gg][e]; }
    counts[e] = run;
  }
  __syncthreads();
  int run = base[g][e];
  for (int b = g * 32; b < g * 32 + 32; ++b) {
    offs[b * NEXP + e] = run;
    run += hist[b * NEXP + e];
  }
}

// ---------------- K3: positions via ballot ----------------------------------
__global__ __launch_bounds__(64) void pos_k(
    const int* __restrict__ route, const float* __restrict__ prob,
    const int* __restrict__ offs, const float* __restrict__ x,
    float* __restrict__ out, int* __restrict__ lists) {
  int tid = threadIdx.x;
  int t = blockIdx.x * 64 + tid;
  int r = route[t];
  unsigned long long lower = (1ull << tid) - 1ull;
  int rank = 0;
#pragma unroll
  for (int e = 0; e < NEXP; ++e) {
    unsigned long long m = __ballot(r == e);
    if (r == e) rank = __popcll(m & lower);
  }
  int pos = offs[blockIdx.x * NEXP + r] + rank;
  if (pos < CAP) {
    lists[r * CAPP + pos] = t;
  } else {
    float p = prob[t];
    const float4* xr = (const float4*)(x + (size_t)t * DIM);
    float4* o = (float4*)(out + (size_t)t * DIM);
    for (int d = 0; d < DIM / 4; ++d) {
      float4 v = xr[d];
      v.x *= p; v.y *= p; v.z *= p; v.w *= p;
      o[d] = v;
    }
  }
}

// ---------------- K4: grouped GEMM, m97 structure ---------------------------
#define BM 128
#define BN 128
#define BKS 64

__global__ __launch_bounds__(256, 2) void gemm_k(
    const short* __restrict__ x_bf, const short* __restrict__ w_bf,
    const float* __restrict__ eb, const int* __restrict__ lists,
    const int* __restrict__ counts, const float* __restrict__ prob,
    float* __restrict__ out) {
  int e = blockIdx.z;
  int cnt = counts[e]; if (cnt > CAP) cnt = CAP;
  int row0 = blockIdx.y * BM;
  if (row0 >= cnt) return;
  int col0 = blockIdx.x * BN;

  __shared__ short A_s[BM * BKS];
  __shared__ short B_s[BN * BKS];
  __shared__ int rowtok[BM];

  int tid = threadIdx.x;
  if (tid < BM) {
    int gr = row0 + tid;
    rowtok[tid] = (gr < cnt) ? lists[e * CAPP + gr] : 0;
  }
  __syncthreads();

  int wv = tid >> 6, lane = tid & 63;
  int q = lane >> 4, l16 = lane & 15;
  int wrow = (wv >> 1) * 64, wcol = (wv & 1) * 64;

  int r_loc = lane >> 3, c = lane & 7;
  int g = c ^ r_loc;
  const short* ga[4]; const short* gb[4];
  short* la[4]; short* lb[4];
#pragma unroll
  for (int t4 = 0; t4 < 4; ++t4) {
    int row = wv * 32 + t4 * 8 + r_loc;
    ga[t4] = x_bf + (size_t)rowtok[row] * DIM + g * 8;
    gb[t4] = w_bf + (size_t)(e * DIM + col0 + row) * DIM + g * 8;
    la[t4] = &A_s[(wv * 32 + t4 * 8) * BKS];   // wave-uniform base
    lb[t4] = &B_s[(wv * 32 + t4 * 8) * BKS];
  }

  floatx4 acc[4][4] = {};

  for (int k0 = 0; k0 < DIM; k0 += BKS) {
#pragma unroll
    for (int t4 = 0; t4 < 4; ++t4) {
      __builtin_amdgcn_global_load_lds(
          (const __attribute__((address_space(1))) void*)(ga[t4] + k0),
          (__attribute__((address_space(3))) void*)(la[t4]), 16, 0, 0);
      __builtin_amdgcn_global_load_lds(
          (const __attribute__((address_space(1))) void*)(gb[t4] + k0),
          (__attribute__((address_space(3))) void*)(lb[t4]), 16, 0, 0);
    }
    __syncthreads();
#pragma unroll
    for (int kk = 0; kk < 2; ++kk) {
      short8 af[4], bfv[4];
      int ckbase = kk * 4 + q;
#pragma unroll
      for (int sm = 0; sm < 4; ++sm) {
        int row = wrow + sm * 16 + l16;
        int ph = ckbase ^ (row & 7);
        af[sm] = *(const short8*)&A_s[row * BKS + ph * 8];
      }
#pragma unroll
      for (int sn = 0; sn < 4; ++sn) {
        int row = wcol + sn * 16 + l16;
        int ph = ckbase ^ (row & 7);
        bfv[sn] = *(const short8*)&B_s[row * BKS + ph * 8];
      }
#pragma unroll
      for (int sm = 0; sm < 4; ++sm)
#pragma unroll
        for (int sn = 0; sn < 4; ++sn)
          acc[sm][sn] = __builtin_amdgcn_mfma_f32_16x16x32_bf16(
              af[sm], bfv[sn], acc[sm][sn], 0, 0, 0);
    }
    __syncthreads();
  }

#pragma unroll
  for (int sm = 0; sm < 4; ++sm) {
    int tt[4]; float pp[4]; int vld[4];
#pragma unroll
    for (int rg = 0; rg < 4; ++rg) {
      int rr = wrow + sm * 16 + q * 4 + rg;
      int gr = row0 + rr;
      vld[rg] = (gr < cnt);
      tt[rg]  = rowtok[rr];
      pp[rg]  = vld[rg] ? prob[tt[rg]] : 0.f;
    }
#pragma unroll
    for (int sn = 0; sn < 4; ++sn) {
      int col = col0 + wcol + sn * 16 + l16;
      float bias = eb[e * DIM + col];
#pragma unroll
      for (int rg = 0; rg < 4; ++rg)
        if (vld[rg])
          out[(size_t)tt[rg] * DIM + col] = (acc[sm][sn][rg] + bias) * pp[rg];
    }
  }
}

extern "C" void kernel_launch(void* const* d_in, const int* in_sizes, int n_in,
                              void* d_out, int out_size, void* d_ws, size_t ws_size,
                              hipStream_t stream) {
  const float* x  = (const float*)d_in[0];
  const float* sw = (const float*)d_in[1];
  const float* sb = (const float*)d_in[2];
  const float* ew = (const float*)d_in[3];
  const float* eb = (const float*)d_in[4];
  float* out = (float*)d_out;

  char* ws = (char*)d_ws;
  int*   route  = (int*)(ws + 0);
  float* prob   = (float*)(ws + 131072);
  int*   hist   = (int*)(ws + 262144);
  int*   offs   = (int*)(ws + 294912);
  int*   counts = (int*)(ws + 327680);
  int*   lists  = (int*)(ws + 327744);
  short* x_bf   = (short*)(ws + (1 << 20));
  short* w_bf   = (short*)(ws + (1 << 20) + 33554432);

  hipLaunchKernelGGL(router_k, dim3(NCHUNK), dim3(256), 0, stream,
                     x, sw, sb, ew, route, prob, hist, x_bf, w_bf);
  hipLaunchKernelGGL(scan_k, dim3(1), dim3(256), 0, stream, hist, offs, counts);
  hipLaunchKernelGGL(pos_k, dim3(NCHUNK), dim3(64), 0, stream,
                     route, prob, offs, x, out, lists);
  hipLaunchKernelGGL(gemm_k, dim3(4, 20, 16), dim3(256), 0, stream,
                     x_bf, w_bf, eb, lists, counts, prob, out);
}

// Round 4
// 183.618 us; speedup vs baseline: 1.6367x; 1.0059x over previous
//
#include <hip/hip_runtime.h>
#include <math.h>

#define N_TOK 32768
#define DIM   512
#define NEXP  16
#define CAP   2457
#define CAPP  2464
#define NCHUNK 512   // chunks of 64 tokens

typedef __attribute__((ext_vector_type(8))) short   short8;
typedef __attribute__((ext_vector_type(4))) short   short4v;
typedef __attribute__((ext_vector_type(4))) float   floatx4;

__device__ __forceinline__ short f2bf(float f) {
  unsigned u = __builtin_bit_cast(unsigned, f);
  unsigned r = u + 0x7FFFu + ((u >> 16) & 1u);   // round-to-nearest-even bf16
  return (short)(r >> 16);
}
__device__ __forceinline__ float bf2f(short h) {
  return __builtin_bit_cast(float, ((unsigned)(unsigned short)h) << 16);
}

// ---------------- K1: MFMA router (split-bf16 hi/lo, 4-term) ----------------
#define LGP 17
__global__ __launch_bounds__(256) void router_k(
    const float* __restrict__ x, const float* __restrict__ sw,
    const float* __restrict__ sb, const float* __restrict__ ew,
    int* __restrict__ route, float* __restrict__ prob, int* __restrict__ hist,
    short* __restrict__ x_bf, short* __restrict__ w_bf) {
  __shared__ short swh[16][520];
  __shared__ short swl[16][520];
  __shared__ float lgt[64][LGP];
  __shared__ float sbs[NEXP];

  int tid = threadIdx.x;

  // folded convw: this block converts 2048 float4 of expert_w
  {
    const float4* src = (const float4*)ew;
    short4v* dst = (short4v*)w_bf;
    int base = blockIdx.x * 2048 + tid;
#pragma unroll
    for (int i = 0; i < 8; ++i) {
      float4 f = src[base + i * 256];
      short4v s;
      s[0] = f2bf(f.x); s[1] = f2bf(f.y); s[2] = f2bf(f.z); s[3] = f2bf(f.w);
      dst[base + i * 256] = s;
    }
  }

  // stage sw hi/lo into LDS
  {
    int idx = tid;
#pragma unroll
    for (int i = 0; i < 8; ++i, idx += 256) {
      int e = idx >> 7, k4 = idx & 127;
      float4 f = ((const float4*)(sw + e * DIM))[k4];
      short4v h, l;
      h[0] = f2bf(f.x); h[1] = f2bf(f.y); h[2] = f2bf(f.z); h[3] = f2bf(f.w);
      l[0] = f2bf(f.x - bf2f(h[0]));
      l[1] = f2bf(f.y - bf2f(h[1]));
      l[2] = f2bf(f.z - bf2f(h[2]));
      l[3] = f2bf(f.w - bf2f(h[3]));
      *(short4v*)&swh[e][k4 * 4] = h;
      *(short4v*)&swl[e][k4 * 4] = l;
    }
  }
  if (tid < NEXP) sbs[tid] = sb[tid];
  __syncthreads();

  int wv = tid >> 6, lane = tid & 63, q = lane >> 4, l16 = lane & 15;
  int row = blockIdx.x * 64 + wv * 16 + l16;
  const float* xr = x + (size_t)row * DIM;
  short* xbr = x_bf + (size_t)row * DIM;

  floatx4 acc = {};
#pragma unroll 4
  for (int kc = 0; kc < 16; ++kc) {
    int k0 = kc * 32 + q * 8;
    float4 f0 = *(const float4*)(xr + k0);
    float4 f1 = *(const float4*)(xr + k0 + 4);
    short8 hi, lo;
    hi[0] = f2bf(f0.x); hi[1] = f2bf(f0.y); hi[2] = f2bf(f0.z); hi[3] = f2bf(f0.w);
    hi[4] = f2bf(f1.x); hi[5] = f2bf(f1.y); hi[6] = f2bf(f1.z); hi[7] = f2bf(f1.w);
    lo[0] = f2bf(f0.x - bf2f(hi[0])); lo[1] = f2bf(f0.y - bf2f(hi[1]));
    lo[2] = f2bf(f0.z - bf2f(hi[2])); lo[3] = f2bf(f0.w - bf2f(hi[3]));
    lo[4] = f2bf(f1.x - bf2f(hi[4])); lo[5] = f2bf(f1.y - bf2f(hi[5]));
    lo[6] = f2bf(f1.z - bf2f(hi[6])); lo[7] = f2bf(f1.w - bf2f(hi[7]));
    *(short8*)(xbr + k0) = hi;
    short8 bh = *(const short8*)&swh[l16][k0];
    short8 bl = *(const short8*)&swl[l16][k0];
    acc = __builtin_amdgcn_mfma_f32_16x16x32_bf16(hi, bh, acc, 0, 0, 0);
    acc = __builtin_amdgcn_mfma_f32_16x16x32_bf16(lo, bh, acc, 0, 0, 0);
    acc = __builtin_amdgcn_mfma_f32_16x16x32_bf16(hi, bl, acc, 0, 0, 0);
    acc = __builtin_amdgcn_mfma_f32_16x16x32_bf16(lo, bl, acc, 0, 0, 0);
  }
#pragma unroll
  for (int r = 0; r < 4; ++r)
    lgt[wv * 16 + q * 4 + r][l16] = acc[r];
  __syncthreads();

  if (tid < 64) {
    int t = blockIdx.x * 64 + tid;
    float lg[NEXP];
#pragma unroll
    for (int e = 0; e < NEXP; ++e) lg[e] = lgt[tid][e] + sbs[e];
    int arg = 0; float mx = lg[0];
#pragma unroll
    for (int e = 1; e < NEXP; ++e)
      if (lg[e] > mx) { mx = lg[e]; arg = e; }
    float s = 0.f;
#pragma unroll
    for (int e = 0; e < NEXP; ++e) s += expf(lg[e] - mx);
    route[t] = arg;
    prob[t]  = 1.0f / s;
#pragma unroll
    for (int e = 0; e < NEXP; ++e) {
      unsigned long long m = __ballot(arg == e);
      if (tid == e) hist[blockIdx.x * NEXP + e] = __popcll(m);
    }
  }
}

// ---------------- K2: positions + fused chunk-prefix scan -------------------
// 128 blocks x 256 threads; block b handles tokens [b*256, b*256+256)
// = chunks 4b..4b+3. Each block redundantly computes its prefix from hist
// (no dispatch-order assumptions). Block 127 writes counts[].
__global__ __launch_bounds__(256) void pos_k(
    const int* __restrict__ route, const float* __restrict__ prob,
    const int* __restrict__ hist, const float* __restrict__ x,
    float* __restrict__ out, int* __restrict__ lists,
    int* __restrict__ counts) {
  __shared__ int part[16][NEXP];
  __shared__ int base_s[NEXP];
  __shared__ int wcnt[4][NEXP];
  int tid = threadIdx.x;
  int b = blockIdx.x;
  int c0 = b * 4;
  {
    int g = tid >> 4, e = tid & 15;
    int s = 0;
    for (int c = g; c < c0; c += 16) s += hist[c * NEXP + e];
    part[g][e] = s;
  }
  __syncthreads();
  if (tid < NEXP) {
    int s = 0;
#pragma unroll
    for (int gg = 0; gg < 16; ++gg) s += part[gg][tid];
    base_s[tid] = s;
  }
  int wv = tid >> 6, lane = tid & 63;
  int t = b * 256 + wv * 64 + lane;
  int r = route[t];
  unsigned long long lower = (1ull << lane) - 1ull;
  int rank = 0;
#pragma unroll
  for (int e = 0; e < NEXP; ++e) {
    unsigned long long m = __ballot(r == e);
    if (r == e) rank = __popcll(m & lower);
    if (lane == e) wcnt[wv][e] = __popcll(m);
  }
  __syncthreads();
  int pre = base_s[r];
  for (int w2 = 0; w2 < wv; ++w2) pre += wcnt[w2][r];
  int pos = pre + rank;
  if (pos < CAP) {
    lists[r * CAPP + pos] = t;
  } else {
    float p = prob[t];
    const float4* xr = (const float4*)(x + (size_t)t * DIM);
    float4* o = (float4*)(out + (size_t)t * DIM);
    for (int d = 0; d < DIM / 4; ++d) {
      float4 v = xr[d];
      v.x *= p; v.y *= p; v.z *= p; v.w *= p;
      o[d] = v;
    }
  }
  if (b == 127 && tid < NEXP)
    counts[tid] = base_s[tid] + wcnt[0][tid] + wcnt[1][tid]
                + wcnt[2][tid] + wcnt[3][tid];
}

// ---------------- K3: grouped GEMM, 64x128 tile for 2x occupancy ------------
#define BM 64
#define BN 128
#define BKS 64

__global__ __launch_bounds__(256, 4) void gemm_k(
    const short* __restrict__ x_bf, const short* __restrict__ w_bf,
    const float* __restrict__ eb, const int* __restrict__ lists,
    const int* __restrict__ counts, const float* __restrict__ prob,
    float* __restrict__ out) {
  int e = blockIdx.z;
  int cnt = counts[e]; if (cnt > CAP) cnt = CAP;
  int row0 = blockIdx.y * BM;
  if (row0 >= cnt) return;
  int col0 = blockIdx.x * BN;

  __shared__ short A_s[BM * BKS];
  __shared__ short B_s[BN * BKS];
  __shared__ int rowtok[BM];

  int tid = threadIdx.x;
  if (tid < BM) {
    int gr = row0 + tid;
    rowtok[tid] = (gr < cnt) ? lists[e * CAPP + gr] : 0;
  }
  __syncthreads();

  int wv = tid >> 6, lane = tid & 63;
  int q = lane >> 4, l16 = lane & 15;
  int wrow = (wv >> 1) * 32, wcol = (wv & 1) * 64;

  // staging lane map: 8 rows x 8 chunks of 16B per wave-instruction
  int r_loc = lane >> 3, c = lane & 7;
  const short* ga[2]; short* la[2];
  const short* gb[4]; short* lb[4];
#pragma unroll
  for (int t2 = 0; t2 < 2; ++t2) {
    int row = wv * 16 + t2 * 8 + r_loc;
    int g = c ^ (row & 7);
    ga[t2] = x_bf + (size_t)rowtok[row] * DIM + g * 8;
    la[t2] = &A_s[(wv * 16 + t2 * 8) * BKS];     // wave-uniform base
  }
#pragma unroll
  for (int t4 = 0; t4 < 4; ++t4) {
    int row = wv * 32 + t4 * 8 + r_loc;
    int g = c ^ (row & 7);
    gb[t4] = w_bf + (size_t)(e * DIM + col0 + row) * DIM + g * 8;
    lb[t4] = &B_s[(wv * 32 + t4 * 8) * BKS];
  }

  floatx4 acc[2][4] = {};

  for (int k0 = 0; k0 < DIM; k0 += BKS) {
#pragma unroll
    for (int t2 = 0; t2 < 2; ++t2)
      __builtin_amdgcn_global_load_lds(
          (const __attribute__((address_space(1))) void*)(ga[t2] + k0),
          (__attribute__((address_space(3))) void*)(la[t2]), 16, 0, 0);
#pragma unroll
    for (int t4 = 0; t4 < 4; ++t4)
      __builtin_amdgcn_global_load_lds(
          (const __attribute__((address_space(1))) void*)(gb[t4] + k0),
          (__attribute__((address_space(3))) void*)(lb[t4]), 16, 0, 0);
    __syncthreads();
#pragma unroll
    for (int kk = 0; kk < 2; ++kk) {
      short8 af[2], bfv[4];
      int ckbase = kk * 4 + q;
#pragma unroll
      for (int sm = 0; sm < 2; ++sm) {
        int row = wrow + sm * 16 + l16;
        int ph = ckbase ^ (row & 7);
        af[sm] = *(const short8*)&A_s[row * BKS + ph * 8];
      }
#pragma unroll
      for (int sn = 0; sn < 4; ++sn) {
        int row = wcol + sn * 16 + l16;
        int ph = ckbase ^ (row & 7);
        bfv[sn] = *(const short8*)&B_s[row * BKS + ph * 8];
      }
#pragma unroll
      for (int sm = 0; sm < 2; ++sm)
#pragma unroll
        for (int sn = 0; sn < 4; ++sn)
          acc[sm][sn] = __builtin_amdgcn_mfma_f32_16x16x32_bf16(
              af[sm], bfv[sn], acc[sm][sn], 0, 0, 0);
    }
    __syncthreads();
  }

#pragma unroll
  for (int sm = 0; sm < 2; ++sm) {
    int tt[4]; float pp[4]; int vld[4];
#pragma unroll
    for (int rg = 0; rg < 4; ++rg) {
      int rr = wrow + sm * 16 + q * 4 + rg;
      int gr = row0 + rr;
      vld[rg] = (gr < cnt);
      tt[rg]  = rowtok[rr];
      pp[rg]  = vld[rg] ? prob[tt[rg]] : 0.f;
    }
#pragma unroll
    for (int sn = 0; sn < 4; ++sn) {
      int col = col0 + wcol + sn * 16 + l16;
      float bias = eb[e * DIM + col];
#pragma unroll
      for (int rg = 0; rg < 4; ++rg)
        if (vld[rg])
          out[(size_t)tt[rg] * DIM + col] = (acc[sm][sn][rg] + bias) * pp[rg];
    }
  }
}

extern "C" void kernel_launch(void* const* d_in, const int* in_sizes, int n_in,
                              void* d_out, int out_size, void* d_ws, size_t ws_size,
                              hipStream_t stream) {
  const float* x  = (const float*)d_in[0];
  const float* sw = (const float*)d_in[1];
  const float* sb = (const float*)d_in[2];
  const float* ew = (const float*)d_in[3];
  const float* eb = (const float*)d_in[4];
  float* out = (float*)d_out;

  char* ws = (char*)d_ws;
  int*   route  = (int*)(ws + 0);
  float* prob   = (float*)(ws + 131072);
  int*   hist   = (int*)(ws + 262144);
  int*   counts = (int*)(ws + 327680);
  int*   lists  = (int*)(ws + 327744);
  short* x_bf   = (short*)(ws + (1 << 20));
  short* w_bf   = (short*)(ws + (1 << 20) + 33554432);

  hipLaunchKernelGGL(router_k, dim3(NCHUNK), dim3(256), 0, stream,
                     x, sw, sb, ew, route, prob, hist, x_bf, w_bf);
  hipLaunchKernelGGL(pos_k, dim3(128), dim3(256), 0, stream,
                     route, prob, hist, x, out, lists, counts);
  hipLaunchKernelGGL(gemm_k, dim3(4, 39, 16), dim3(256), 0, stream,
                     x_bf, w_bf, eb, lists, counts, prob, out);
}